// Round 7
// baseline (497.380 us; speedup 1.0000x reference)
//
#include <hip/hip_runtime.h>
#include <math.h>

// Relational Network fused pipeline for MI355X (gfx950).
// B=32, D=64, K=26, QST=256, G=[512x6, 28], AGG at layer 4.
//
// Round 12 changes vs rounds 10/11:
//  - Round 11's 4-deep pipeline spilled again (compiler caps arch VGPRs at
//    ~128 when AGPRs are used; 144-reg demand -> 63MB scratch). Reverted to
//    round 10's proven schedule shape.
//  - ROOT BOTTLENECK identified by arithmetic: round 10's k-step streamed
//    32KB/CU of B-weights from L2 (~585 cyc) vs 621 cyc of MFMA -> the loop
//    ran at ~94% of per-CU L2 BW (3.2GB/dispatch: every one of 2048 blocks
//    reads the full 1.5MB Wp). Fix: M=128 tile. One block = TWO p-values
//    (128 pair-rows), h tile 128x512 bf16 = 128KB LDS (+16KB xs = 144 <=
//    160KB), grid 1024. Same B bytes now feed 2x MFMAs -> B L2 time halves
//    (~293 vs 1242 cyc/step) -> MFMA-bound.
//  - Registers under the empirical cap: acc[8][4] = 128 AGPR; arch side via
//    mt-OUTER clusters with ROLLING A (A[mt] dead after its 4-MFMA cluster,
//    reload in place for s+1: 7-cluster distance > LDS latency; 32 regs) +
//    B X/Y ping-pong (X reloaded at odd-step top for s+2: >= full-step
//    distance > L2 latency; 32 regs). ~90 arch total.
//  - Occupancy unchanged (LDS already forced 1 block/CU). launch_bounds(512,2).

typedef __attribute__((ext_vector_type(8))) short bf16x8;   // 8 bf16 in 4 VGPRs
typedef __attribute__((ext_vector_type(4))) float f32x4;    // MFMA 16x16 accumulator
typedef __attribute__((ext_vector_type(4))) unsigned int u32x4;

__device__ __forceinline__ unsigned short f2bf(float f) {
    union { float f; unsigned u; } x; x.f = f;
    unsigned r = x.u + 0x7fffu + ((x.u >> 16) & 1u);   // RNE
    return (unsigned short)(r >> 16);
}

// ---------------- pack / transpose weights ----------------
// Wp layout per layer: [wave(8)][s(16)][jj(4)][lane(64)][j(8)] bf16,
//   value = W[n][k], n = (wave*4+jj)*16 + (lane&15), k = s*32 + (lane>>4)*8 + j.
// W0p: same with s(2) over padded K=64 (k >= 52 -> 0).
// W4v/W5v: fp32 [k/4][512 out][4] so k_tail threads stream float4.
#define NP_WP   786432            // 3 * 512*512
#define NP_W0P  32768             // 512*64 (K padded 52->64)
#define NP_W4T  393216            // 512*768
#define NP_W5T  262144            // 512*512
#define NP_TOTAL (NP_WP + NP_W0P + NP_W4T + NP_W5T)   // 1474560 = 5760*256
__global__ void k_prep(const float* __restrict__ W1, const float* __restrict__ W2,
                       const float* __restrict__ W3, const float* __restrict__ W0,
                       const float* __restrict__ W4, const float* __restrict__ W5,
                       unsigned short* __restrict__ Wp,   // [3][262144] bf16
                       unsigned short* __restrict__ W0p,  // [32768] bf16
                       float* __restrict__ W4v,           // [192][512][4] fp32
                       float* __restrict__ W5v)           // [128][512][4] fp32
{
    int f = blockIdx.x * 256 + threadIdx.x;
    if (f < NP_WP) {
        int l = f >> 18, r = f & 262143;
        int n = r >> 9, k = r & 511;                    // read W[n*512+k] coalesced
        const float* W = (l == 0) ? W1 : (l == 1) ? W2 : W3;
        float v = W[r];
        int wv = n >> 6, jj = (n >> 4) & 3, i16 = n & 15;
        int s = k >> 5, q4 = (k >> 3) & 3, j = k & 7;
        int lane = q4 * 16 + i16;
        Wp[(size_t)l * 262144 + ((((wv * 16 + s) * 4 + jj) * 64 + lane) << 3) + j] = f2bf(v);
    } else if (f < NP_WP + NP_W0P) {
        int g = f - NP_WP;
        int n = g >> 6, k = g & 63;
        float v = (k < 52) ? W0[n * 52 + k] : 0.f;
        int wv = n >> 6, jj = (n >> 4) & 3, i16 = n & 15;
        int s = k >> 5, q4 = (k >> 3) & 3, j = k & 7;
        int lane = q4 * 16 + i16;
        W0p[((((wv * 2 + s) * 4 + jj) * 64 + lane) << 3) + j] = f2bf(v);
    } else if (f < NP_WP + NP_W0P + NP_W4T) {
        int g = f - (NP_WP + NP_W0P);
        int o = g / 768, k = g % 768;                   // read W4[g] coalesced
        W4v[(size_t)((k >> 2) * 512 + o) * 4 + (k & 3)] = W4[g];
    } else {
        int g = f - (NP_WP + NP_W0P + NP_W4T);
        int o = g >> 9, k = g & 511;                    // read W5[g] coalesced
        W5v[(size_t)((k >> 2) * 512 + o) * 4 + (k & 3)] = W5[g];
    }
}

// ---------------- h-store epilogue: bias + relu + bf16 LDS write ----
// Granule-column-major (128-row): byte = (col>>3)*2048 + ((row^((col>>3)&7)))*16
//                                       + (col&7)*2.
// DPP quad_perm swap on f32, then v_cvt_pk_bf16_f32 packs (col, col+1) into
// one dword; even lanes write ds_write_b32.
__device__ __forceinline__ void store_h(const f32x4 (&acc)[8][4], const float* __restrict__ bl,
                                        unsigned short* hsm, int wave, int i16, int q4, int lane)
{
    char* base = (char*)hsm;
    #pragma unroll
    for (int j = 0; j < 4; ++j) {
        int col = (wave * 4 + j) * 16 + i16;
        int g = col >> 3;
        int e = g & 7;
        float bb = bl[col];
        char* colbase = base + g * 2048 + ((col & 7) << 1);
        #pragma unroll
        for (int mt = 0; mt < 8; ++mt) {
            #pragma unroll
            for (int r = 0; r < 4; ++r) {
                int row = mt * 16 + q4 * 4 + r;
                float v = fmaxf(acc[mt][j][r] + bb, 0.f);
                int vi = __float_as_int(v);
                // quad_perm [1,0,3,2]: each lane gets partner (lane^1)'s f32
                int swi = __builtin_amdgcn_update_dpp(0, vi, 0xB1, 0xF, 0xF, true);
                if ((lane & 1) == 0) {
                    unsigned pk;
                    asm("v_cvt_pk_bf16_f32 %0, %1, %2" : "=v"(pk) : "v"(vi), "v"(swi));
                    int slot = row ^ e;
                    *(unsigned*)(colbase + slot * 16) = pk;
                }
            }
        }
    }
}

// mt-cluster: 4 MFMAs (j=0..3) consuming one A fragment + the 4 live B frags.
#define CLUSTER(AV, B0v, B1v, B2v, B3v, MT)                                               \
    __builtin_amdgcn_s_setprio(1);                                                       \
    acc[MT][0] = __builtin_amdgcn_mfma_f32_16x16x32_bf16(AV, B0v, acc[MT][0], 0, 0, 0);  \
    acc[MT][1] = __builtin_amdgcn_mfma_f32_16x16x32_bf16(AV, B1v, acc[MT][1], 0, 0, 0);  \
    acc[MT][2] = __builtin_amdgcn_mfma_f32_16x16x32_bf16(AV, B2v, acc[MT][2], 0, 0, 0);  \
    acc[MT][3] = __builtin_amdgcn_mfma_f32_16x16x32_bf16(AV, B3v, acc[MT][3], 0, 0, 0);  \
    __builtin_amdgcn_s_setprio(0);                                                       \
    __builtin_amdgcn_sched_barrier(0);

// ---------------- fused layers 0..3 ----------------
// One block per (b, p-pair): 128 pair-rows (rows 0-63: p0, 64-127: p1).
// h tile 128x512 bf16 in LDS, granule-column-major:
//   hsm[g=col>>3][slot=row^(g&7)][8 shorts], column stride 2048 B.
// 8 waves; wave w computes cols [w*64, w*64+64): acc = 8 (row tiles) x 4 (col tiles).
__global__ __launch_bounds__(512, 2) void k_fused(
    const float* __restrict__ x,
    const unsigned short* __restrict__ Wp,
    const unsigned short* __restrict__ W0p,
    const float* __restrict__ b0, const float* __restrict__ b1,
    const float* __restrict__ b2, const float* __restrict__ b3,
    float* __restrict__ P)
{
    __shared__ __align__(16) unsigned short hsm[128 * 512];   // 128 KiB
    __shared__ __align__(16) unsigned short xs[8 * 128 * 8];  // 16 KiB (x-pair tile)
    int t = threadIdx.x;
    int blk = blockIdx.x;
    int b = blk >> 5, pw = blk & 31;      // p0 = 2*pw, p1 = 2*pw+1

    // ---- stage xs: [g(8)][slot=row^g][8] bf16 of [x[b,q,:26] | x[b,p,:26] | 0],
    //      rows 0-63 -> p0, rows 64-127 -> p1; 4 threads per row ----
    {
        int row = t >> 2, sub = t & 3;
        int q = row & 63;
        int pp = (pw << 1) + (row >> 6);
        const float* xq = x + (size_t)(b * 64 + q) * 26;
        const float* xp = x + (size_t)(b * 64 + pp) * 26;
        #pragma unroll
        for (int gi = 0; gi < 2; ++gi) {
            int g = sub * 2 + gi;
            unsigned w[4];
            #pragma unroll
            for (int h = 0; h < 4; ++h) {
                int k0 = g * 8 + h * 2;
                int k1 = k0 + 1;
                float f0 = (k0 < 26) ? xq[k0] : (k0 < 52 ? xp[k0 - 26] : 0.f);
                float f1 = (k1 < 26) ? xq[k1] : (k1 < 52 ? xp[k1 - 26] : 0.f);
                w[h] = (unsigned)f2bf(f0) | ((unsigned)f2bf(f1) << 16);
            }
            *(u32x4*)((char*)xs + g * 2048 + ((row ^ g) << 4)) = (u32x4){w[0], w[1], w[2], w[3]};
        }
    }

    int wave = t >> 6, lane = t & 63;
    int i16 = lane & 15, q4 = lane >> 4;

    f32x4 acc[8][4];

    __syncthreads();   // xs ready

    // ---- layer 0: h0 = relu([x_q|x_p] @ W0^T + b0), K=64 padded ----
    {
        #pragma unroll
        for (int mt = 0; mt < 8; ++mt)
            #pragma unroll
            for (int j = 0; j < 4; ++j)
                acc[mt][j] = (f32x4){0.f, 0.f, 0.f, 0.f};
        const unsigned short* Bb0 = W0p + wave * 4096 + lane * 8;
        const char* xb = (const char*)xs;
        #pragma unroll
        for (int s = 0; s < 2; ++s) {
            bf16x8 bfr[4];
            #pragma unroll
            for (int j = 0; j < 4; ++j)
                bfr[j] = *(const bf16x8*)(Bb0 + s * 2048 + j * 512);
            int g = s * 4 + q4;
            const char* A0 = xb + g * 2048 + ((i16 ^ (g & 7)) << 4);
            #pragma unroll
            for (int mt = 0; mt < 8; ++mt) {
                bf16x8 a = *(const bf16x8*)(A0 + mt * 256);
                #pragma unroll
                for (int j = 0; j < 4; ++j)
                    acc[mt][j] = __builtin_amdgcn_mfma_f32_16x16x32_bf16(a, bfr[j], acc[mt][j], 0, 0, 0);
            }
        }
        store_h(acc, b0, hsm, wave, i16, q4, lane);   // each wave writes its own cols
    }

    // ---- layers 1..3: mt-outer rolling-A + B X/Y ping-pong ----
    // A byte addr for step s: [parity base] + s*8192 + mt*256.
    int A_evenoff = (q4 << 11) + ((i16 ^ q4) << 4);
    const char* hbe = (const char*)hsm + A_evenoff;          // even-step A base
    const char* hbo = (const char*)hsm + (A_evenoff ^ 64);   // odd-step A base

    #pragma unroll 1
    for (int l = 0; l < 3; ++l) {
        const float* bl = (l == 0) ? b1 : (l == 1) ? b2 : b3;
        // B fragments: one shared per-lane address; j at +1024B, s at +4096B.
        const unsigned short* Bb = Wp + (size_t)l * 262144 + wave * 32768 + lane * 8;

        // prefetch B(0) -> X, B(1) -> Y; these ride the barrier drain
        bf16x8 X0 = *(const bf16x8*)(Bb);
        bf16x8 X1 = *(const bf16x8*)(Bb + 512);
        bf16x8 X2 = *(const bf16x8*)(Bb + 1024);
        bf16x8 X3 = *(const bf16x8*)(Bb + 1536);
        bf16x8 Y0 = *(const bf16x8*)(Bb + 2048);
        bf16x8 Y1 = *(const bf16x8*)(Bb + 2560);
        bf16x8 Y2 = *(const bf16x8*)(Bb + 3072);
        bf16x8 Y3 = *(const bf16x8*)(Bb + 3584);

        __syncthreads();   // h ready

        #pragma unroll
        for (int mt = 0; mt < 8; ++mt)
            #pragma unroll
            for (int j = 0; j < 4; ++j)
                acc[mt][j] = (f32x4){0.f, 0.f, 0.f, 0.f};

        // A(0)
        bf16x8 A0 = *(const bf16x8*)(hbe);
        bf16x8 A1 = *(const bf16x8*)(hbe + 256);
        bf16x8 A2 = *(const bf16x8*)(hbe + 512);
        bf16x8 A3 = *(const bf16x8*)(hbe + 768);
        bf16x8 A4 = *(const bf16x8*)(hbe + 1024);
        bf16x8 A5 = *(const bf16x8*)(hbe + 1280);
        bf16x8 A6 = *(const bf16x8*)(hbe + 1536);
        bf16x8 A7 = *(const bf16x8*)(hbe + 1792);

        #pragma unroll 1
        for (int s = 0; s < 16; s += 2) {
            int s2 = (s + 2 < 16) ? s + 2 : 14;            // clamped (tail dummies)
            int s3 = (s + 3 < 16) ? s + 3 : 15;
            const char* pnO = hbo + ((s + 1) << 13);       // A(s+1), odd
            const char* pnE = hbe + (s2 << 13);            // A(s+2), even
            const unsigned short* BX = Bb + s2 * 2048;     // B(s+2) -> X
            const unsigned short* BY = Bb + s3 * 2048;     // B(s+3) -> Y

            // ===== even step s: consume A,X; reload A[mt] <- A(s+1) after use =====
            CLUSTER(A0, X0, X1, X2, X3, 0)  A0 = *(const bf16x8*)(pnO);
            CLUSTER(A1, X0, X1, X2, X3, 1)  A1 = *(const bf16x8*)(pnO + 256);
            CLUSTER(A2, X0, X1, X2, X3, 2)  A2 = *(const bf16x8*)(pnO + 512);
            CLUSTER(A3, X0, X1, X2, X3, 3)  A3 = *(const bf16x8*)(pnO + 768);
            CLUSTER(A4, X0, X1, X2, X3, 4)  A4 = *(const bf16x8*)(pnO + 1024);
            CLUSTER(A5, X0, X1, X2, X3, 5)  A5 = *(const bf16x8*)(pnO + 1280);
            CLUSTER(A6, X0, X1, X2, X3, 6)  A6 = *(const bf16x8*)(pnO + 1536);
            CLUSTER(A7, X0, X1, X2, X3, 7)  A7 = *(const bf16x8*)(pnO + 1792);

            // ===== odd step s+1: X dead -> reload X <- B(s+2) up front =====
            X0 = *(const bf16x8*)(BX);
            X1 = *(const bf16x8*)(BX + 512);
            X2 = *(const bf16x8*)(BX + 1024);
            X3 = *(const bf16x8*)(BX + 1536);
            // consume A,Y; reload A[mt] <- A(s+2) after use
            CLUSTER(A0, Y0, Y1, Y2, Y3, 0)  A0 = *(const bf16x8*)(pnE);
            CLUSTER(A1, Y0, Y1, Y2, Y3, 1)  A1 = *(const bf16x8*)(pnE + 256);
            CLUSTER(A2, Y0, Y1, Y2, Y3, 2)  A2 = *(const bf16x8*)(pnE + 512);
            CLUSTER(A3, Y0, Y1, Y2, Y3, 3)  A3 = *(const bf16x8*)(pnE + 768);
            CLUSTER(A4, Y0, Y1, Y2, Y3, 4)  A4 = *(const bf16x8*)(pnE + 1024);
            CLUSTER(A5, Y0, Y1, Y2, Y3, 5)  A5 = *(const bf16x8*)(pnE + 1280);
            CLUSTER(A6, Y0, Y1, Y2, Y3, 6)  A6 = *(const bf16x8*)(pnE + 1536);
            CLUSTER(A7, Y0, Y1, Y2, Y3, 7)  A7 = *(const bf16x8*)(pnE + 1792);
            // Y dead -> reload Y <- B(s+3)
            Y0 = *(const bf16x8*)(BY);
            Y1 = *(const bf16x8*)(BY + 512);
            Y2 = *(const bf16x8*)(BY + 1024);
            Y3 = *(const bf16x8*)(BY + 1536);
        }
        __syncthreads();   // all reads of h done before overwrite

        if (l < 2) {
            store_h(acc, bl, hsm, wave, i16, q4, lane);
        } else {
            // layer 3: bias + relu + sum over all 128 rows -> per-block partial
            #pragma unroll
            for (int j = 0; j < 4; ++j) {
                int col = (wave * 4 + j) * 16 + i16;
                float bb = bl[col];
                float sum = 0.f;
                #pragma unroll
                for (int mt = 0; mt < 8; ++mt)
                    #pragma unroll
                    for (int r = 0; r < 4; ++r)
                        sum += fmaxf(acc[mt][j][r] + bb, 0.f);
                sum += __shfl_xor(sum, 16);
                sum += __shfl_xor(sum, 32);
                if (q4 == 0) P[(size_t)blk * 512 + col] = sum;
            }
        }
    }
}

// ---------------- tail: reduce P + layers 4,5,6 + log_softmax ----
__global__ __launch_bounds__(1024) void k_tail(
    const float* __restrict__ P, const float* __restrict__ qst,
    const float* __restrict__ W4v, const float* __restrict__ b4,
    const float* __restrict__ W5v, const float* __restrict__ b5,
    const float* __restrict__ W6, const float* __restrict__ b6,
    float* __restrict__ out)
{
    int b = blockIdx.x, t = threadIdx.x;
    __shared__ __align__(16) float z[768];
    __shared__ __align__(16) float ps[1024];
    __shared__ __align__(16) float h4[512];
    __shared__ float h5[512];
    __shared__ float logits[28];
    __shared__ float red[2];

    if (t < 512) {     // reduce the 32 per-(b,p-pair)-block partials
        float s = 0.f;
        const float* Pb = P + (size_t)b * 32 * 512 + t;
        #pragma unroll 8
        for (int c = 0; c < 32; ++c) s += Pb[c * 512];
        z[t] = s;
    } else if (t < 768) {
        z[t] = qst[b * 256 + (t - 512)];
    }
    __syncthreads();
    {   // layer 4: 768 -> 512, 2-way k-split per output
        int o = t & 511, hf = t >> 9;
        float acc = 0.f;
        const float4* Wv = (const float4*)W4v;
        const float4* z4 = (const float4*)z;
        #pragma unroll 4
        for (int kb = hf * 96; kb < hf * 96 + 96; ++kb) {
            float4 w = Wv[kb * 512 + o];
            float4 zz = z4[kb];
            acc = fmaf(w.x, zz.x, acc);
            acc = fmaf(w.y, zz.y, acc);
            acc = fmaf(w.z, zz.z, acc);
            acc = fmaf(w.w, zz.w, acc);
        }
        ps[t] = acc;
    }
    __syncthreads();
    if (t < 512) h4[t] = fmaxf(ps[t] + ps[t + 512] + b4[t], 0.f);
    __syncthreads();
    {   // layer 5: 512 -> 512, 2-way k-split per output
        int o = t & 511, hf = t >> 9;
        float acc = 0.f;
        const float4* Wv = (const float4*)W5v;
        const float4* h44 = (const float4*)h4;
        #pragma unroll 4
        for (int kb = hf * 64; kb < hf * 64 + 64; ++kb) {
            float4 w = Wv[kb * 512 + o];
            float4 hh = h44[kb];
            acc = fmaf(w.x, hh.x, acc);
            acc = fmaf(w.y, hh.y, acc);
            acc = fmaf(w.z, hh.z, acc);
            acc = fmaf(w.w, hh.w, acc);
        }
        ps[t] = acc;
    }
    __syncthreads();
    if (t < 512) h5[t] = fmaxf(ps[t] + ps[t + 512] + b5[t], 0.f);
    __syncthreads();
    {   // layer 6: 512 -> 28 (32 lanes per output)
        int o = t >> 5, c = t & 31;
        if (o < 28) {
            float acc = 0.f;
            for (int k = c; k < 512; k += 32) acc = fmaf(W6[o * 512 + k], h5[k], acc);
            acc += __shfl_xor(acc, 1);
            acc += __shfl_xor(acc, 2);
            acc += __shfl_xor(acc, 4);
            acc += __shfl_xor(acc, 8);
            acc += __shfl_xor(acc, 16);
            if (c == 0) logits[o] = acc + b6[o];
        }
    }
    __syncthreads();
    if (t == 0) {
        float mx = -1e30f;
        for (int cc = 0; cc < 28; ++cc) mx = fmaxf(mx, logits[cc]);
        float se = 0.f;
        for (int cc = 0; cc < 28; ++cc) se += expf(logits[cc] - mx);
        red[0] = mx; red[1] = logf(se);
    }
    __syncthreads();
    if (t < 28) out[b * 28 + t] = logits[t] - red[0] - red[1];
}

extern "C" void kernel_launch(void* const* d_in, const int* in_sizes, int n_in,
                              void* d_out, int out_size, void* d_ws, size_t ws_size,
                              hipStream_t stream)
{
    const float* x   = (const float*)d_in[0];
    const float* qst = (const float*)d_in[1];
    const float* W0  = (const float*)d_in[2];
    const float* b0  = (const float*)d_in[3];
    const float* W1  = (const float*)d_in[4];
    const float* b1  = (const float*)d_in[5];
    const float* W2  = (const float*)d_in[6];
    const float* b2  = (const float*)d_in[7];
    const float* W3  = (const float*)d_in[8];
    const float* b3  = (const float*)d_in[9];
    const float* W4  = (const float*)d_in[10];
    const float* b4  = (const float*)d_in[11];
    const float* W5  = (const float*)d_in[12];
    const float* b5  = (const float*)d_in[13];
    const float* W6  = (const float*)d_in[14];
    const float* b6  = (const float*)d_in[15];
    float* out = (float*)d_out;

    char* ws = (char*)d_ws;
    unsigned short* Wp  = (unsigned short*)(ws);             // 1.5 MiB
    unsigned short* W0p = (unsigned short*)(ws + 1572864);   // 64 KiB
    float*          W4v = (float*)(ws + 1638400);            // 1.5 MiB
    float*          W5v = (float*)(ws + 3211264);            // 1 MiB
    float*          P   = (float*)(ws + 4259840);            // 2 MiB partials

    k_prep <<<NP_TOTAL / 256, 256, 0, stream>>>(W1, W2, W3, W0, W4, W5,
                                                Wp, W0p, W4v, W5v);
    k_fused<<<1024, 512, 0, stream>>>(x, Wp, W0p, b0, b1, b2, b3, P);
    k_tail <<<32, 1024, 0, stream>>>(P, qst, W4v, b4, W5v, b5, W6, b6, out);
}

// Round 8
// 486.815 us; speedup vs baseline: 1.0217x; 1.0217x over previous
//
#include <hip/hip_runtime.h>
#include <math.h>

// Relational Network fused pipeline for MI355X (gfx950).
// B=32, D=64, K=26, QST=256, G=[512x6, 28], AGG at layer 4.
//
// Round 13 changes vs round 12:
//  - Round 12's M=128 tile spilled NOT in the k-loop (live ~212 < 256) but
//    in the epilogues: store_h / P-sum read 128 accumulator values and the
//    scheduler BATCHES v_accvgpr_read hoisting -> ~128 arch temporaries on
//    top of loop state -> 312B/thread scratch (160MB WRITE, L3-thrashing).
//    Rounds 10/11 passed with 64 acc values purely because the batch fit.
//    Fix: __builtin_amdgcn_sched_barrier(0) fences inside store_h (per
//    mt-group of 4 values), the layer-3 P-sum (per mt), and layer-0's
//    cluster loop -> caps transient reads to <=4.
//  - Everything else identical to round 12: one block = 2 p-values
//    (128 rows), h 128x512 bf16 (128KB LDS), grid 1024, acc[8][4]=128 AGPR,
//    rolling-A + X/Y B ping-pong, launch_bounds(512,2).
//  - Why M=128: k-loop is per-CU L2-read bound (32KB B-weights per k-step
//    ~ 1100-1300cyc at sustained ~28B/cyc/CU vs 310cyc MFMA). M=128 halves
//    total steps chip-wide at the same per-step L2 cost.

typedef __attribute__((ext_vector_type(8))) short bf16x8;   // 8 bf16 in 4 VGPRs
typedef __attribute__((ext_vector_type(4))) float f32x4;    // MFMA 16x16 accumulator
typedef __attribute__((ext_vector_type(4))) unsigned int u32x4;

__device__ __forceinline__ unsigned short f2bf(float f) {
    union { float f; unsigned u; } x; x.f = f;
    unsigned r = x.u + 0x7fffu + ((x.u >> 16) & 1u);   // RNE
    return (unsigned short)(r >> 16);
}

// ---------------- pack / transpose weights ----------------
// Wp layout per layer: [wave(8)][s(16)][jj(4)][lane(64)][j(8)] bf16,
//   value = W[n][k], n = (wave*4+jj)*16 + (lane&15), k = s*32 + (lane>>4)*8 + j.
// W0p: same with s(2) over padded K=64 (k >= 52 -> 0).
// W4v/W5v: fp32 [k/4][512 out][4] so k_tail threads stream float4.
#define NP_WP   786432            // 3 * 512*512
#define NP_W0P  32768             // 512*64 (K padded 52->64)
#define NP_W4T  393216            // 512*768
#define NP_W5T  262144            // 512*512
#define NP_TOTAL (NP_WP + NP_W0P + NP_W4T + NP_W5T)   // 1474560 = 5760*256
__global__ void k_prep(const float* __restrict__ W1, const float* __restrict__ W2,
                       const float* __restrict__ W3, const float* __restrict__ W0,
                       const float* __restrict__ W4, const float* __restrict__ W5,
                       unsigned short* __restrict__ Wp,   // [3][262144] bf16
                       unsigned short* __restrict__ W0p,  // [32768] bf16
                       float* __restrict__ W4v,           // [192][512][4] fp32
                       float* __restrict__ W5v)           // [128][512][4] fp32
{
    int f = blockIdx.x * 256 + threadIdx.x;
    if (f < NP_WP) {
        int l = f >> 18, r = f & 262143;
        int n = r >> 9, k = r & 511;                    // read W[n*512+k] coalesced
        const float* W = (l == 0) ? W1 : (l == 1) ? W2 : W3;
        float v = W[r];
        int wv = n >> 6, jj = (n >> 4) & 3, i16 = n & 15;
        int s = k >> 5, q4 = (k >> 3) & 3, j = k & 7;
        int lane = q4 * 16 + i16;
        Wp[(size_t)l * 262144 + ((((wv * 16 + s) * 4 + jj) * 64 + lane) << 3) + j] = f2bf(v);
    } else if (f < NP_WP + NP_W0P) {
        int g = f - NP_WP;
        int n = g >> 6, k = g & 63;
        float v = (k < 52) ? W0[n * 52 + k] : 0.f;
        int wv = n >> 6, jj = (n >> 4) & 3, i16 = n & 15;
        int s = k >> 5, q4 = (k >> 3) & 3, j = k & 7;
        int lane = q4 * 16 + i16;
        W0p[((((wv * 2 + s) * 4 + jj) * 64 + lane) << 3) + j] = f2bf(v);
    } else if (f < NP_WP + NP_W0P + NP_W4T) {
        int g = f - (NP_WP + NP_W0P);
        int o = g / 768, k = g % 768;                   // read W4[g] coalesced
        W4v[(size_t)((k >> 2) * 512 + o) * 4 + (k & 3)] = W4[g];
    } else {
        int g = f - (NP_WP + NP_W0P + NP_W4T);
        int o = g >> 9, k = g & 511;                    // read W5[g] coalesced
        W5v[(size_t)((k >> 2) * 512 + o) * 4 + (k & 3)] = W5[g];
    }
}

// ---------------- h-store epilogue: bias + relu + bf16 LDS write ----
// Granule-column-major (128-row): byte = (col>>3)*2048 + ((row^((col>>3)&7)))*16
//                                       + (col&7)*2.
// DPP quad_perm swap on f32, then v_cvt_pk_bf16_f32 packs (col, col+1) into
// one dword; even lanes write ds_write_b32.
// sched_barrier(0) per mt-group caps the accvgpr-read batch (spill guard).
__device__ __forceinline__ void store_h(const f32x4 (&acc)[8][4], const float* __restrict__ bl,
                                        unsigned short* hsm, int wave, int i16, int q4, int lane)
{
    char* base = (char*)hsm;
    #pragma unroll
    for (int j = 0; j < 4; ++j) {
        int col = (wave * 4 + j) * 16 + i16;
        int g = col >> 3;
        int e = g & 7;
        float bb = bl[col];
        char* colbase = base + g * 2048 + ((col & 7) << 1);
        #pragma unroll
        for (int mt = 0; mt < 8; ++mt) {
            #pragma unroll
            for (int r = 0; r < 4; ++r) {
                int row = mt * 16 + q4 * 4 + r;
                float v = fmaxf(acc[mt][j][r] + bb, 0.f);
                int vi = __float_as_int(v);
                // quad_perm [1,0,3,2]: each lane gets partner (lane^1)'s f32
                int swi = __builtin_amdgcn_update_dpp(0, vi, 0xB1, 0xF, 0xF, true);
                if ((lane & 1) == 0) {
                    unsigned pk;
                    asm("v_cvt_pk_bf16_f32 %0, %1, %2" : "=v"(pk) : "v"(vi), "v"(swi));
                    int slot = row ^ e;
                    *(unsigned*)(colbase + slot * 16) = pk;
                }
            }
            __builtin_amdgcn_sched_barrier(0);   // cap live acc-read transients
        }
    }
}

// mt-cluster: 4 MFMAs (j=0..3) consuming one A fragment + the 4 live B frags.
#define CLUSTER(AV, B0v, B1v, B2v, B3v, MT)                                               \
    __builtin_amdgcn_s_setprio(1);                                                       \
    acc[MT][0] = __builtin_amdgcn_mfma_f32_16x16x32_bf16(AV, B0v, acc[MT][0], 0, 0, 0);  \
    acc[MT][1] = __builtin_amdgcn_mfma_f32_16x16x32_bf16(AV, B1v, acc[MT][1], 0, 0, 0);  \
    acc[MT][2] = __builtin_amdgcn_mfma_f32_16x16x32_bf16(AV, B2v, acc[MT][2], 0, 0, 0);  \
    acc[MT][3] = __builtin_amdgcn_mfma_f32_16x16x32_bf16(AV, B3v, acc[MT][3], 0, 0, 0);  \
    __builtin_amdgcn_s_setprio(0);                                                       \
    __builtin_amdgcn_sched_barrier(0);

// ---------------- fused layers 0..3 ----------------
// One block per (b, p-pair): 128 pair-rows (rows 0-63: p0, 64-127: p1).
// h tile 128x512 bf16 in LDS, granule-column-major:
//   hsm[g=col>>3][slot=row^(g&7)][8 shorts], column stride 2048 B.
// 8 waves; wave w computes cols [w*64, w*64+64): acc = 8 (row tiles) x 4 (col tiles).
__global__ __launch_bounds__(512, 2) void k_fused(
    const float* __restrict__ x,
    const unsigned short* __restrict__ Wp,
    const unsigned short* __restrict__ W0p,
    const float* __restrict__ b0, const float* __restrict__ b1,
    const float* __restrict__ b2, const float* __restrict__ b3,
    float* __restrict__ P)
{
    __shared__ __align__(16) unsigned short hsm[128 * 512];   // 128 KiB
    __shared__ __align__(16) unsigned short xs[8 * 128 * 8];  // 16 KiB (x-pair tile)
    int t = threadIdx.x;
    int blk = blockIdx.x;
    int b = blk >> 5, pw = blk & 31;      // p0 = 2*pw, p1 = 2*pw+1

    // ---- stage xs: [g(8)][slot=row^g][8] bf16 of [x[b,q,:26] | x[b,p,:26] | 0],
    //      rows 0-63 -> p0, rows 64-127 -> p1; 4 threads per row ----
    {
        int row = t >> 2, sub = t & 3;
        int q = row & 63;
        int pp = (pw << 1) + (row >> 6);
        const float* xq = x + (size_t)(b * 64 + q) * 26;
        const float* xp = x + (size_t)(b * 64 + pp) * 26;
        #pragma unroll
        for (int gi = 0; gi < 2; ++gi) {
            int g = sub * 2 + gi;
            unsigned w[4];
            #pragma unroll
            for (int h = 0; h < 4; ++h) {
                int k0 = g * 8 + h * 2;
                int k1 = k0 + 1;
                float f0 = (k0 < 26) ? xq[k0] : (k0 < 52 ? xp[k0 - 26] : 0.f);
                float f1 = (k1 < 26) ? xq[k1] : (k1 < 52 ? xp[k1 - 26] : 0.f);
                w[h] = (unsigned)f2bf(f0) | ((unsigned)f2bf(f1) << 16);
            }
            *(u32x4*)((char*)xs + g * 2048 + ((row ^ g) << 4)) = (u32x4){w[0], w[1], w[2], w[3]};
        }
    }

    int wave = t >> 6, lane = t & 63;
    int i16 = lane & 15, q4 = lane >> 4;

    f32x4 acc[8][4];

    __syncthreads();   // xs ready

    // ---- layer 0: h0 = relu([x_q|x_p] @ W0^T + b0), K=64 padded ----
    {
        #pragma unroll
        for (int mt = 0; mt < 8; ++mt)
            #pragma unroll
            for (int j = 0; j < 4; ++j)
                acc[mt][j] = (f32x4){0.f, 0.f, 0.f, 0.f};
        const unsigned short* Bb0 = W0p + wave * 4096 + lane * 8;
        const char* xb = (const char*)xs;
        #pragma unroll
        for (int s = 0; s < 2; ++s) {
            bf16x8 bfr[4];
            #pragma unroll
            for (int j = 0; j < 4; ++j)
                bfr[j] = *(const bf16x8*)(Bb0 + s * 2048 + j * 512);
            int g = s * 4 + q4;
            const char* A0 = xb + g * 2048 + ((i16 ^ (g & 7)) << 4);
            #pragma unroll
            for (int mt = 0; mt < 8; ++mt) {
                bf16x8 a = *(const bf16x8*)(A0 + mt * 256);
                #pragma unroll
                for (int j = 0; j < 4; ++j)
                    acc[mt][j] = __builtin_amdgcn_mfma_f32_16x16x32_bf16(a, bfr[j], acc[mt][j], 0, 0, 0);
                __builtin_amdgcn_sched_barrier(0);   // cap A-load batching
            }
        }
        store_h(acc, b0, hsm, wave, i16, q4, lane);   // each wave writes its own cols
    }

    // ---- layers 1..3: mt-outer rolling-A + B X/Y ping-pong ----
    // A byte addr for step s: [parity base] + s*8192 + mt*256.
    int A_evenoff = (q4 << 11) + ((i16 ^ q4) << 4);
    const char* hbe = (const char*)hsm + A_evenoff;          // even-step A base
    const char* hbo = (const char*)hsm + (A_evenoff ^ 64);   // odd-step A base

    #pragma unroll 1
    for (int l = 0; l < 3; ++l) {
        const float* bl = (l == 0) ? b1 : (l == 1) ? b2 : b3;
        // B fragments: one shared per-lane address; j at +1024B, s at +4096B.
        const unsigned short* Bb = Wp + (size_t)l * 262144 + wave * 32768 + lane * 8;

        // prefetch B(0) -> X, B(1) -> Y; these ride the barrier drain
        bf16x8 X0 = *(const bf16x8*)(Bb);
        bf16x8 X1 = *(const bf16x8*)(Bb + 512);
        bf16x8 X2 = *(const bf16x8*)(Bb + 1024);
        bf16x8 X3 = *(const bf16x8*)(Bb + 1536);
        bf16x8 Y0 = *(const bf16x8*)(Bb + 2048);
        bf16x8 Y1 = *(const bf16x8*)(Bb + 2560);
        bf16x8 Y2 = *(const bf16x8*)(Bb + 3072);
        bf16x8 Y3 = *(const bf16x8*)(Bb + 3584);

        __syncthreads();   // h ready

        #pragma unroll
        for (int mt = 0; mt < 8; ++mt)
            #pragma unroll
            for (int j = 0; j < 4; ++j)
                acc[mt][j] = (f32x4){0.f, 0.f, 0.f, 0.f};

        // A(0)
        bf16x8 A0 = *(const bf16x8*)(hbe);
        bf16x8 A1 = *(const bf16x8*)(hbe + 256);
        bf16x8 A2 = *(const bf16x8*)(hbe + 512);
        bf16x8 A3 = *(const bf16x8*)(hbe + 768);
        bf16x8 A4 = *(const bf16x8*)(hbe + 1024);
        bf16x8 A5 = *(const bf16x8*)(hbe + 1280);
        bf16x8 A6 = *(const bf16x8*)(hbe + 1536);
        bf16x8 A7 = *(const bf16x8*)(hbe + 1792);

        #pragma unroll 1
        for (int s = 0; s < 16; s += 2) {
            int s2 = (s + 2 < 16) ? s + 2 : 14;            // clamped (tail dummies)
            int s3 = (s + 3 < 16) ? s + 3 : 15;
            const char* pnO = hbo + ((s + 1) << 13);       // A(s+1), odd
            const char* pnE = hbe + (s2 << 13);            // A(s+2), even
            const unsigned short* BX = Bb + s2 * 2048;     // B(s+2) -> X
            const unsigned short* BY = Bb + s3 * 2048;     // B(s+3) -> Y

            // ===== even step s: consume A,X; reload A[mt] <- A(s+1) after use =====
            CLUSTER(A0, X0, X1, X2, X3, 0)  A0 = *(const bf16x8*)(pnO);
            CLUSTER(A1, X0, X1, X2, X3, 1)  A1 = *(const bf16x8*)(pnO + 256);
            CLUSTER(A2, X0, X1, X2, X3, 2)  A2 = *(const bf16x8*)(pnO + 512);
            CLUSTER(A3, X0, X1, X2, X3, 3)  A3 = *(const bf16x8*)(pnO + 768);
            CLUSTER(A4, X0, X1, X2, X3, 4)  A4 = *(const bf16x8*)(pnO + 1024);
            CLUSTER(A5, X0, X1, X2, X3, 5)  A5 = *(const bf16x8*)(pnO + 1280);
            CLUSTER(A6, X0, X1, X2, X3, 6)  A6 = *(const bf16x8*)(pnO + 1536);
            CLUSTER(A7, X0, X1, X2, X3, 7)  A7 = *(const bf16x8*)(pnO + 1792);

            // ===== odd step s+1: X dead -> reload X <- B(s+2) up front =====
            X0 = *(const bf16x8*)(BX);
            X1 = *(const bf16x8*)(BX + 512);
            X2 = *(const bf16x8*)(BX + 1024);
            X3 = *(const bf16x8*)(BX + 1536);
            // consume A,Y; reload A[mt] <- A(s+2) after use
            CLUSTER(A0, Y0, Y1, Y2, Y3, 0)  A0 = *(const bf16x8*)(pnE);
            CLUSTER(A1, Y0, Y1, Y2, Y3, 1)  A1 = *(const bf16x8*)(pnE + 256);
            CLUSTER(A2, Y0, Y1, Y2, Y3, 2)  A2 = *(const bf16x8*)(pnE + 512);
            CLUSTER(A3, Y0, Y1, Y2, Y3, 3)  A3 = *(const bf16x8*)(pnE + 768);
            CLUSTER(A4, Y0, Y1, Y2, Y3, 4)  A4 = *(const bf16x8*)(pnE + 1024);
            CLUSTER(A5, Y0, Y1, Y2, Y3, 5)  A5 = *(const bf16x8*)(pnE + 1280);
            CLUSTER(A6, Y0, Y1, Y2, Y3, 6)  A6 = *(const bf16x8*)(pnE + 1536);
            CLUSTER(A7, Y0, Y1, Y2, Y3, 7)  A7 = *(const bf16x8*)(pnE + 1792);
            // Y dead -> reload Y <- B(s+3)
            Y0 = *(const bf16x8*)(BY);
            Y1 = *(const bf16x8*)(BY + 512);
            Y2 = *(const bf16x8*)(BY + 1024);
            Y3 = *(const bf16x8*)(BY + 1536);
        }
        __syncthreads();   // all reads of h done before overwrite

        if (l < 2) {
            store_h(acc, bl, hsm, wave, i16, q4, lane);
        } else {
            // layer 3: bias + relu + sum over all 128 rows -> per-block partial
            #pragma unroll
            for (int j = 0; j < 4; ++j) {
                int col = (wave * 4 + j) * 16 + i16;
                float bb = bl[col];
                float sum = 0.f;
                #pragma unroll
                for (int mt = 0; mt < 8; ++mt) {
                    #pragma unroll
                    for (int r = 0; r < 4; ++r)
                        sum += fmaxf(acc[mt][j][r] + bb, 0.f);
                    __builtin_amdgcn_sched_barrier(0);   // cap acc-read batching
                }
                sum += __shfl_xor(sum, 16);
                sum += __shfl_xor(sum, 32);
                if (q4 == 0) P[(size_t)blk * 512 + col] = sum;
            }
        }
    }
}

// ---------------- tail: reduce P + layers 4,5,6 + log_softmax ----
__global__ __launch_bounds__(1024) void k_tail(
    const float* __restrict__ P, const float* __restrict__ qst,
    const float* __restrict__ W4v, const float* __restrict__ b4,
    const float* __restrict__ W5v, const float* __restrict__ b5,
    const float* __restrict__ W6, const float* __restrict__ b6,
    float* __restrict__ out)
{
    int b = blockIdx.x, t = threadIdx.x;
    __shared__ __align__(16) float z[768];
    __shared__ __align__(16) float ps[1024];
    __shared__ __align__(16) float h4[512];
    __shared__ float h5[512];
    __shared__ float logits[28];
    __shared__ float red[2];

    if (t < 512) {     // reduce the 32 per-(b,p-pair)-block partials
        float s = 0.f;
        const float* Pb = P + (size_t)b * 32 * 512 + t;
        #pragma unroll 8
        for (int c = 0; c < 32; ++c) s += Pb[c * 512];
        z[t] = s;
    } else if (t < 768) {
        z[t] = qst[b * 256 + (t - 512)];
    }
    __syncthreads();
    {   // layer 4: 768 -> 512, 2-way k-split per output
        int o = t & 511, hf = t >> 9;
        float acc = 0.f;
        const float4* Wv = (const float4*)W4v;
        const float4* z4 = (const float4*)z;
        #pragma unroll 4
        for (int kb = hf * 96; kb < hf * 96 + 96; ++kb) {
            float4 w = Wv[kb * 512 + o];
            float4 zz = z4[kb];
            acc = fmaf(w.x, zz.x, acc);
            acc = fmaf(w.y, zz.y, acc);
            acc = fmaf(w.z, zz.z, acc);
            acc = fmaf(w.w, zz.w, acc);
        }
        ps[t] = acc;
    }
    __syncthreads();
    if (t < 512) h4[t] = fmaxf(ps[t] + ps[t + 512] + b4[t], 0.f);
    __syncthreads();
    {   // layer 5: 512 -> 512, 2-way k-split per output
        int o = t & 511, hf = t >> 9;
        float acc = 0.f;
        const float4* Wv = (const float4*)W5v;
        const float4* h44 = (const float4*)h4;
        #pragma unroll 4
        for (int kb = hf * 64; kb < hf * 64 + 64; ++kb) {
            float4 w = Wv[kb * 512 + o];
            float4 hh = h44[kb];
            acc = fmaf(w.x, hh.x, acc);
            acc = fmaf(w.y, hh.y, acc);
            acc = fmaf(w.z, hh.z, acc);
            acc = fmaf(w.w, hh.w, acc);
        }
        ps[t] = acc;
    }
    __syncthreads();
    if (t < 512) h5[t] = fmaxf(ps[t] + ps[t + 512] + b5[t], 0.f);
    __syncthreads();
    {   // layer 6: 512 -> 28 (32 lanes per output)
        int o = t >> 5, c = t & 31;
        if (o < 28) {
            float acc = 0.f;
            for (int k = c; k < 512; k += 32) acc = fmaf(W6[o * 512 + k], h5[k], acc);
            acc += __shfl_xor(acc, 1);
            acc += __shfl_xor(acc, 2);
            acc += __shfl_xor(acc, 4);
            acc += __shfl_xor(acc, 8);
            acc += __shfl_xor(acc, 16);
            if (c == 0) logits[o] = acc + b6[o];
        }
    }
    __syncthreads();
    if (t == 0) {
        float mx = -1e30f;
        for (int cc = 0; cc < 28; ++cc) mx = fmaxf(mx, logits[cc]);
        float se = 0.f;
        for (int cc = 0; cc < 28; ++cc) se += expf(logits[cc] - mx);
        red[0] = mx; red[1] = logf(se);
    }
    __syncthreads();
    if (t < 28) out[b * 28 + t] = logits[t] - red[0] - red[1];
}

extern "C" void kernel_launch(void* const* d_in, const int* in_sizes, int n_in,
                              void* d_out, int out_size, void* d_ws, size_t ws_size,
                              hipStream_t stream)
{
    const float* x   = (const float*)d_in[0];
    const float* qst = (const float*)d_in[1];
    const float* W0  = (const float*)d_in[2];
    const float* b0  = (const float*)d_in[3];
    const float* W1  = (const float*)d_in[4];
    const float* b1  = (const float*)d_in[5];
    const float* W2  = (const float*)d_in[6];
    const float* b2  = (const float*)d_in[7];
    const float* W3  = (const float*)d_in[8];
    const float* b3  = (const float*)d_in[9];
    const float* W4  = (const float*)d_in[10];
    const float* b4  = (const float*)d_in[11];
    const float* W5  = (const float*)d_in[12];
    const float* b5  = (const float*)d_in[13];
    const float* W6  = (const float*)d_in[14];
    const float* b6  = (const float*)d_in[15];
    float* out = (float*)d_out;

    char* ws = (char*)d_ws;
    unsigned short* Wp  = (unsigned short*)(ws);             // 1.5 MiB
    unsigned short* W0p = (unsigned short*)(ws + 1572864);   // 64 KiB
    float*          W4v = (float*)(ws + 1638400);            // 1.5 MiB
    float*          W5v = (float*)(ws + 3211264);            // 1 MiB
    float*          P   = (float*)(ws + 4259840);            // 2 MiB partials

    k_prep <<<NP_TOTAL / 256, 256, 0, stream>>>(W1, W2, W3, W0, W4, W5,
                                                Wp, W0p, W4v, W5v);
    k_fused<<<1024, 512, 0, stream>>>(x, Wp, W0p, b0, b1, b2, b3, P);
    k_tail <<<32, 1024, 0, stream>>>(P, qst, W4v, b4, W5v, b5, W6, b6, out);
}

// Round 10
// 486.769 us; speedup vs baseline: 1.0218x; 1.0001x over previous
//
#include <hip/hip_runtime.h>
#include <math.h>

// Relational Network fused pipeline for MI355X (gfx950).
// B=32, D=64, K=26, QST=256, G=[512x6, 28], AGG at layer 4.
//
// Round 15 = round 14 resubmitted verbatim (bench infra failed: "container
// failed twice" before any run; no counters). The A/B under test:
//  - ONE-LINE ROOT FIX: __launch_bounds__(512, 1) on k_fused. Evidence from
//    rounds 6-13: (512,4) always capped VGPR_Count at 64, (512,2) at 128 ->
//    this toolchain treats the 2nd arg as MIN BLOCKS PER CU (CUDA
//    semantics): cap = 2048 / (8 waves * arg) = 256/arg. Every spill
//    (rounds 11/12/13) was demand exceeding that cap, not the unified-file
//    limit. LDS (144KB) already forces 1 block/CU, so (512,1) changes
//    nothing about occupancy (8 waves/CU) but doubles the register budget
//    to 256/wave. Round 13's structure (M=128 tile, acc[8][4]=128,
//    rolling-A + X/Y B ping-pong, demand ~210) now fits.
//  - Everything else identical to round 13.

typedef __attribute__((ext_vector_type(8))) short bf16x8;   // 8 bf16 in 4 VGPRs
typedef __attribute__((ext_vector_type(4))) float f32x4;    // MFMA 16x16 accumulator
typedef __attribute__((ext_vector_type(4))) unsigned int u32x4;

__device__ __forceinline__ unsigned short f2bf(float f) {
    union { float f; unsigned u; } x; x.f = f;
    unsigned r = x.u + 0x7fffu + ((x.u >> 16) & 1u);   // RNE
    return (unsigned short)(r >> 16);
}

// ---------------- pack / transpose weights ----------------
// Wp layout per layer: [wave(8)][s(16)][jj(4)][lane(64)][j(8)] bf16,
//   value = W[n][k], n = (wave*4+jj)*16 + (lane&15), k = s*32 + (lane>>4)*8 + j.
// W0p: same with s(2) over padded K=64 (k >= 52 -> 0).
// W4v/W5v: fp32 [k/4][512 out][4] so k_tail threads stream float4.
#define NP_WP   786432            // 3 * 512*512
#define NP_W0P  32768             // 512*64 (K padded 52->64)
#define NP_W4T  393216            // 512*768
#define NP_W5T  262144            // 512*512
#define NP_TOTAL (NP_WP + NP_W0P + NP_W4T + NP_W5T)   // 1474560 = 5760*256
__global__ void k_prep(const float* __restrict__ W1, const float* __restrict__ W2,
                       const float* __restrict__ W3, const float* __restrict__ W0,
                       const float* __restrict__ W4, const float* __restrict__ W5,
                       unsigned short* __restrict__ Wp,   // [3][262144] bf16
                       unsigned short* __restrict__ W0p,  // [32768] bf16
                       float* __restrict__ W4v,           // [192][512][4] fp32
                       float* __restrict__ W5v)           // [128][512][4] fp32
{
    int f = blockIdx.x * 256 + threadIdx.x;
    if (f < NP_WP) {
        int l = f >> 18, r = f & 262143;
        int n = r >> 9, k = r & 511;                    // read W[n*512+k] coalesced
        const float* W = (l == 0) ? W1 : (l == 1) ? W2 : W3;
        float v = W[r];
        int wv = n >> 6, jj = (n >> 4) & 3, i16 = n & 15;
        int s = k >> 5, q4 = (k >> 3) & 3, j = k & 7;
        int lane = q4 * 16 + i16;
        Wp[(size_t)l * 262144 + ((((wv * 16 + s) * 4 + jj) * 64 + lane) << 3) + j] = f2bf(v);
    } else if (f < NP_WP + NP_W0P) {
        int g = f - NP_WP;
        int n = g >> 6, k = g & 63;
        float v = (k < 52) ? W0[n * 52 + k] : 0.f;
        int wv = n >> 6, jj = (n >> 4) & 3, i16 = n & 15;
        int s = k >> 5, q4 = (k >> 3) & 3, j = k & 7;
        int lane = q4 * 16 + i16;
        W0p[((((wv * 2 + s) * 4 + jj) * 64 + lane) << 3) + j] = f2bf(v);
    } else if (f < NP_WP + NP_W0P + NP_W4T) {
        int g = f - (NP_WP + NP_W0P);
        int o = g / 768, k = g % 768;                   // read W4[g] coalesced
        W4v[(size_t)((k >> 2) * 512 + o) * 4 + (k & 3)] = W4[g];
    } else {
        int g = f - (NP_WP + NP_W0P + NP_W4T);
        int o = g >> 9, k = g & 511;                    // read W5[g] coalesced
        W5v[(size_t)((k >> 2) * 512 + o) * 4 + (k & 3)] = W5[g];
    }
}

// ---------------- h-store epilogue: bias + relu + bf16 LDS write ----
// Granule-column-major (128-row): byte = (col>>3)*2048 + ((row^((col>>3)&7)))*16
//                                       + (col&7)*2.
// DPP quad_perm swap on f32, then v_cvt_pk_bf16_f32 packs (col, col+1) into
// one dword; even lanes write ds_write_b32.
// sched_barrier(0) per mt-group caps the acc-read batch (spill guard).
__device__ __forceinline__ void store_h(const f32x4 (&acc)[8][4], const float* __restrict__ bl,
                                        unsigned short* hsm, int wave, int i16, int q4, int lane)
{
    char* base = (char*)hsm;
    #pragma unroll
    for (int j = 0; j < 4; ++j) {
        int col = (wave * 4 + j) * 16 + i16;
        int g = col >> 3;
        int e = g & 7;
        float bb = bl[col];
        char* colbase = base + g * 2048 + ((col & 7) << 1);
        #pragma unroll
        for (int mt = 0; mt < 8; ++mt) {
            #pragma unroll
            for (int r = 0; r < 4; ++r) {
                int row = mt * 16 + q4 * 4 + r;
                float v = fmaxf(acc[mt][j][r] + bb, 0.f);
                int vi = __float_as_int(v);
                // quad_perm [1,0,3,2]: each lane gets partner (lane^1)'s f32
                int swi = __builtin_amdgcn_update_dpp(0, vi, 0xB1, 0xF, 0xF, true);
                if ((lane & 1) == 0) {
                    unsigned pk;
                    asm("v_cvt_pk_bf16_f32 %0, %1, %2" : "=v"(pk) : "v"(vi), "v"(swi));
                    int slot = row ^ e;
                    *(unsigned*)(colbase + slot * 16) = pk;
                }
            }
            __builtin_amdgcn_sched_barrier(0);   // cap live acc-read transients
        }
    }
}

// mt-cluster: 4 MFMAs (j=0..3) consuming one A fragment + the 4 live B frags.
#define CLUSTER(AV, B0v, B1v, B2v, B3v, MT)                                               \
    __builtin_amdgcn_s_setprio(1);                                                       \
    acc[MT][0] = __builtin_amdgcn_mfma_f32_16x16x32_bf16(AV, B0v, acc[MT][0], 0, 0, 0);  \
    acc[MT][1] = __builtin_amdgcn_mfma_f32_16x16x32_bf16(AV, B1v, acc[MT][1], 0, 0, 0);  \
    acc[MT][2] = __builtin_amdgcn_mfma_f32_16x16x32_bf16(AV, B2v, acc[MT][2], 0, 0, 0);  \
    acc[MT][3] = __builtin_amdgcn_mfma_f32_16x16x32_bf16(AV, B3v, acc[MT][3], 0, 0, 0);  \
    __builtin_amdgcn_s_setprio(0);                                                       \
    __builtin_amdgcn_sched_barrier(0);

// ---------------- fused layers 0..3 ----------------
// One block per (b, p-pair): 128 pair-rows (rows 0-63: p0, 64-127: p1).
// h tile 128x512 bf16 in LDS, granule-column-major:
//   hsm[g=col>>3][slot=row^(g&7)][8 shorts], column stride 2048 B.
// 8 waves; wave w computes cols [w*64, w*64+64): acc = 8 (row tiles) x 4 (col tiles).
__global__ __launch_bounds__(512, 1) void k_fused(
    const float* __restrict__ x,
    const unsigned short* __restrict__ Wp,
    const unsigned short* __restrict__ W0p,
    const float* __restrict__ b0, const float* __restrict__ b1,
    const float* __restrict__ b2, const float* __restrict__ b3,
    float* __restrict__ P)
{
    __shared__ __align__(16) unsigned short hsm[128 * 512];   // 128 KiB
    __shared__ __align__(16) unsigned short xs[8 * 128 * 8];  // 16 KiB (x-pair tile)
    int t = threadIdx.x;
    int blk = blockIdx.x;
    int b = blk >> 5, pw = blk & 31;      // p0 = 2*pw, p1 = 2*pw+1

    // ---- stage xs: [g(8)][slot=row^g][8] bf16 of [x[b,q,:26] | x[b,p,:26] | 0],
    //      rows 0-63 -> p0, rows 64-127 -> p1; 4 threads per row ----
    {
        int row = t >> 2, sub = t & 3;
        int q = row & 63;
        int pp = (pw << 1) + (row >> 6);
        const float* xq = x + (size_t)(b * 64 + q) * 26;
        const float* xp = x + (size_t)(b * 64 + pp) * 26;
        #pragma unroll
        for (int gi = 0; gi < 2; ++gi) {
            int g = sub * 2 + gi;
            unsigned w[4];
            #pragma unroll
            for (int h = 0; h < 4; ++h) {
                int k0 = g * 8 + h * 2;
                int k1 = k0 + 1;
                float f0 = (k0 < 26) ? xq[k0] : (k0 < 52 ? xp[k0 - 26] : 0.f);
                float f1 = (k1 < 26) ? xq[k1] : (k1 < 52 ? xp[k1 - 26] : 0.f);
                w[h] = (unsigned)f2bf(f0) | ((unsigned)f2bf(f1) << 16);
            }
            *(u32x4*)((char*)xs + g * 2048 + ((row ^ g) << 4)) = (u32x4){w[0], w[1], w[2], w[3]};
        }
    }

    int wave = t >> 6, lane = t & 63;
    int i16 = lane & 15, q4 = lane >> 4;

    f32x4 acc[8][4];

    __syncthreads();   // xs ready

    // ---- layer 0: h0 = relu([x_q|x_p] @ W0^T + b0), K=64 padded ----
    {
        #pragma unroll
        for (int mt = 0; mt < 8; ++mt)
            #pragma unroll
            for (int j = 0; j < 4; ++j)
                acc[mt][j] = (f32x4){0.f, 0.f, 0.f, 0.f};
        const unsigned short* Bb0 = W0p + wave * 4096 + lane * 8;
        const char* xb = (const char*)xs;
        #pragma unroll
        for (int s = 0; s < 2; ++s) {
            bf16x8 bfr[4];
            #pragma unroll
            for (int j = 0; j < 4; ++j)
                bfr[j] = *(const bf16x8*)(Bb0 + s * 2048 + j * 512);
            int g = s * 4 + q4;
            const char* A0 = xb + g * 2048 + ((i16 ^ (g & 7)) << 4);
            #pragma unroll
            for (int mt = 0; mt < 8; ++mt) {
                bf16x8 a = *(const bf16x8*)(A0 + mt * 256);
                #pragma unroll
                for (int j = 0; j < 4; ++j)
                    acc[mt][j] = __builtin_amdgcn_mfma_f32_16x16x32_bf16(a, bfr[j], acc[mt][j], 0, 0, 0);
                __builtin_amdgcn_sched_barrier(0);   // cap A-load batching
            }
        }
        store_h(acc, b0, hsm, wave, i16, q4, lane);   // each wave writes its own cols
    }

    // ---- layers 1..3: mt-outer rolling-A + B X/Y ping-pong ----
    // A byte addr for step s: [parity base] + s*8192 + mt*256.
    int A_evenoff = (q4 << 11) + ((i16 ^ q4) << 4);
    const char* hbe = (const char*)hsm + A_evenoff;          // even-step A base
    const char* hbo = (const char*)hsm + (A_evenoff ^ 64);   // odd-step A base

    #pragma unroll 1
    for (int l = 0; l < 3; ++l) {
        const float* bl = (l == 0) ? b1 : (l == 1) ? b2 : b3;
        // B fragments: one shared per-lane address; j at +1024B, s at +4096B.
        const unsigned short* Bb = Wp + (size_t)l * 262144 + wave * 32768 + lane * 8;

        // prefetch B(0) -> X, B(1) -> Y; these ride the barrier drain
        bf16x8 X0 = *(const bf16x8*)(Bb);
        bf16x8 X1 = *(const bf16x8*)(Bb + 512);
        bf16x8 X2 = *(const bf16x8*)(Bb + 1024);
        bf16x8 X3 = *(const bf16x8*)(Bb + 1536);
        bf16x8 Y0 = *(const bf16x8*)(Bb + 2048);
        bf16x8 Y1 = *(const bf16x8*)(Bb + 2560);
        bf16x8 Y2 = *(const bf16x8*)(Bb + 3072);
        bf16x8 Y3 = *(const bf16x8*)(Bb + 3584);

        __syncthreads();   // h ready

        #pragma unroll
        for (int mt = 0; mt < 8; ++mt)
            #pragma unroll
            for (int j = 0; j < 4; ++j)
                acc[mt][j] = (f32x4){0.f, 0.f, 0.f, 0.f};

        // A(0)
        bf16x8 A0 = *(const bf16x8*)(hbe);
        bf16x8 A1 = *(const bf16x8*)(hbe + 256);
        bf16x8 A2 = *(const bf16x8*)(hbe + 512);
        bf16x8 A3 = *(const bf16x8*)(hbe + 768);
        bf16x8 A4 = *(const bf16x8*)(hbe + 1024);
        bf16x8 A5 = *(const bf16x8*)(hbe + 1280);
        bf16x8 A6 = *(const bf16x8*)(hbe + 1536);
        bf16x8 A7 = *(const bf16x8*)(hbe + 1792);

        #pragma unroll 1
        for (int s = 0; s < 16; s += 2) {
            int s2 = (s + 2 < 16) ? s + 2 : 14;            // clamped (tail dummies)
            int s3 = (s + 3 < 16) ? s + 3 : 15;
            const char* pnO = hbo + ((s + 1) << 13);       // A(s+1), odd
            const char* pnE = hbe + (s2 << 13);            // A(s+2), even
            const unsigned short* BX = Bb + s2 * 2048;     // B(s+2) -> X
            const unsigned short* BY = Bb + s3 * 2048;     // B(s+3) -> Y

            // ===== even step s: consume A,X; reload A[mt] <- A(s+1) after use =====
            CLUSTER(A0, X0, X1, X2, X3, 0)  A0 = *(const bf16x8*)(pnO);
            CLUSTER(A1, X0, X1, X2, X3, 1)  A1 = *(const bf16x8*)(pnO + 256);
            CLUSTER(A2, X0, X1, X2, X3, 2)  A2 = *(const bf16x8*)(pnO + 512);
            CLUSTER(A3, X0, X1, X2, X3, 3)  A3 = *(const bf16x8*)(pnO + 768);
            CLUSTER(A4, X0, X1, X2, X3, 4)  A4 = *(const bf16x8*)(pnO + 1024);
            CLUSTER(A5, X0, X1, X2, X3, 5)  A5 = *(const bf16x8*)(pnO + 1280);
            CLUSTER(A6, X0, X1, X2, X3, 6)  A6 = *(const bf16x8*)(pnO + 1536);
            CLUSTER(A7, X0, X1, X2, X3, 7)  A7 = *(const bf16x8*)(pnO + 1792);

            // ===== odd step s+1: X dead -> reload X <- B(s+2) up front =====
            X0 = *(const bf16x8*)(BX);
            X1 = *(const bf16x8*)(BX + 512);
            X2 = *(const bf16x8*)(BX + 1024);
            X3 = *(const bf16x8*)(BX + 1536);
            // consume A,Y; reload A[mt] <- A(s+2) after use
            CLUSTER(A0, Y0, Y1, Y2, Y3, 0)  A0 = *(const bf16x8*)(pnE);
            CLUSTER(A1, Y0, Y1, Y2, Y3, 1)  A1 = *(const bf16x8*)(pnE + 256);
            CLUSTER(A2, Y0, Y1, Y2, Y3, 2)  A2 = *(const bf16x8*)(pnE + 512);
            CLUSTER(A3, Y0, Y1, Y2, Y3, 3)  A3 = *(const bf16x8*)(pnE + 768);
            CLUSTER(A4, Y0, Y1, Y2, Y3, 4)  A4 = *(const bf16x8*)(pnE + 1024);
            CLUSTER(A5, Y0, Y1, Y2, Y3, 5)  A5 = *(const bf16x8*)(pnE + 1280);
            CLUSTER(A6, Y0, Y1, Y2, Y3, 6)  A6 = *(const bf16x8*)(pnE + 1536);
            CLUSTER(A7, Y0, Y1, Y2, Y3, 7)  A7 = *(const bf16x8*)(pnE + 1792);
            // Y dead -> reload Y <- B(s+3)
            Y0 = *(const bf16x8*)(BY);
            Y1 = *(const bf16x8*)(BY + 512);
            Y2 = *(const bf16x8*)(BY + 1024);
            Y3 = *(const bf16x8*)(BY + 1536);
        }
        __syncthreads();   // all reads of h done before overwrite

        if (l < 2) {
            store_h(acc, bl, hsm, wave, i16, q4, lane);
        } else {
            // layer 3: bias + relu + sum over all 128 rows -> per-block partial
            #pragma unroll
            for (int j = 0; j < 4; ++j) {
                int col = (wave * 4 + j) * 16 + i16;
                float bb = bl[col];
                float sum = 0.f;
                #pragma unroll
                for (int mt = 0; mt < 8; ++mt) {
                    #pragma unroll
                    for (int r = 0; r < 4; ++r)
                        sum += fmaxf(acc[mt][j][r] + bb, 0.f);
                    __builtin_amdgcn_sched_barrier(0);   // cap acc-read batching
                }
                sum += __shfl_xor(sum, 16);
                sum += __shfl_xor(sum, 32);
                if (q4 == 0) P[(size_t)blk * 512 + col] = sum;
            }
        }
    }
}

// ---------------- tail: reduce P + layers 4,5,6 + log_softmax ----
__global__ __launch_bounds__(1024) void k_tail(
    const float* __restrict__ P, const float* __restrict__ qst,
    const float* __restrict__ W4v, const float* __restrict__ b4,
    const float* __restrict__ W5v, const float* __restrict__ b5,
    const float* __restrict__ W6, const float* __restrict__ b6,
    float* __restrict__ out)
{
    int b = blockIdx.x, t = threadIdx.x;
    __shared__ __align__(16) float z[768];
    __shared__ __align__(16) float ps[1024];
    __shared__ __align__(16) float h4[512];
    __shared__ float h5[512];
    __shared__ float logits[28];
    __shared__ float red[2];

    if (t < 512) {     // reduce the 32 per-(b,p-pair)-block partials
        float s = 0.f;
        const float* Pb = P + (size_t)b * 32 * 512 + t;
        #pragma unroll 8
        for (int c = 0; c < 32; ++c) s += Pb[c * 512];
        z[t] = s;
    } else if (t < 768) {
        z[t] = qst[b * 256 + (t - 512)];
    }
    __syncthreads();
    {   // layer 4: 768 -> 512, 2-way k-split per output
        int o = t & 511, hf = t >> 9;
        float acc = 0.f;
        const float4* Wv = (const float4*)W4v;
        const float4* z4 = (const float4*)z;
        #pragma unroll 4
        for (int kb = hf * 96; kb < hf * 96 + 96; ++kb) {
            float4 w = Wv[kb * 512 + o];
            float4 zz = z4[kb];
            acc = fmaf(w.x, zz.x, acc);
            acc = fmaf(w.y, zz.y, acc);
            acc = fmaf(w.z, zz.z, acc);
            acc = fmaf(w.w, zz.w, acc);
        }
        ps[t] = acc;
    }
    __syncthreads();
    if (t < 512) h4[t] = fmaxf(ps[t] + ps[t + 512] + b4[t], 0.f);
    __syncthreads();
    {   // layer 5: 512 -> 512, 2-way k-split per output
        int o = t & 511, hf = t >> 9;
        float acc = 0.f;
        const float4* Wv = (const float4*)W5v;
        const float4* h44 = (const float4*)h4;
        #pragma unroll 4
        for (int kb = hf * 64; kb < hf * 64 + 64; ++kb) {
            float4 w = Wv[kb * 512 + o];
            float4 hh = h44[kb];
            acc = fmaf(w.x, hh.x, acc);
            acc = fmaf(w.y, hh.y, acc);
            acc = fmaf(w.z, hh.z, acc);
            acc = fmaf(w.w, hh.w, acc);
        }
        ps[t] = acc;
    }
    __syncthreads();
    if (t < 512) h5[t] = fmaxf(ps[t] + ps[t + 512] + b5[t], 0.f);
    __syncthreads();
    {   // layer 6: 512 -> 28 (32 lanes per output)
        int o = t >> 5, c = t & 31;
        if (o < 28) {
            float acc = 0.f;
            for (int k = c; k < 512; k += 32) acc = fmaf(W6[o * 512 + k], h5[k], acc);
            acc += __shfl_xor(acc, 1);
            acc += __shfl_xor(acc, 2);
            acc += __shfl_xor(acc, 4);
            acc += __shfl_xor(acc, 8);
            acc += __shfl_xor(acc, 16);
            if (c == 0) logits[o] = acc + b6[o];
        }
    }
    __syncthreads();
    if (t == 0) {
        float mx = -1e30f;
        for (int cc = 0; cc < 28; ++cc) mx = fmaxf(mx, logits[cc]);
        float se = 0.f;
        for (int cc = 0; cc < 28; ++cc) se += expf(logits[cc] - mx);
        red[0] = mx; red[1] = logf(se);
    }
    __syncthreads();
    if (t < 28) out[b * 28 + t] = logits[t] - red[0] - red[1];
}

extern "C" void kernel_launch(void* const* d_in, const int* in_sizes, int n_in,
                              void* d_out, int out_size, void* d_ws, size_t ws_size,
                              hipStream_t stream)
{
    const float* x   = (const float*)d_in[0];
    const float* qst = (const float*)d_in[1];
    const float* W0  = (const float*)d_in[2];
    const float* b0  = (const float*)d_in[3];
    const float* W1  = (const float*)d_in[4];
    const float* b1  = (const float*)d_in[5];
    const float* W2  = (const float*)d_in[6];
    const float* b2  = (const float*)d_in[7];
    const float* W3  = (const float*)d_in[8];
    const float* b3  = (const float*)d_in[9];
    const float* W4  = (const float*)d_in[10];
    const float* b4  = (const float*)d_in[11];
    const float* W5  = (const float*)d_in[12];
    const float* b5  = (const float*)d_in[13];
    const float* W6  = (const float*)d_in[14];
    const float* b6  = (const float*)d_in[15];
    float* out = (float*)d_out;

    char* ws = (char*)d_ws;
    unsigned short* Wp  = (unsigned short*)(ws);             // 1.5 MiB
    unsigned short* W0p = (unsigned short*)(ws + 1572864);   // 64 KiB
    float*          W4v = (float*)(ws + 1638400);            // 1.5 MiB
    float*          W5v = (float*)(ws + 3211264);            // 1 MiB
    float*          P   = (float*)(ws + 4259840);            // 2 MiB partials

    k_prep <<<NP_TOTAL / 256, 256, 0, stream>>>(W1, W2, W3, W0, W4, W5,
                                                Wp, W0p, W4v, W5v);
    k_fused<<<1024, 512, 0, stream>>>(x, Wp, W0p, b0, b1, b2, b3, P);
    k_tail <<<32, 1024, 0, stream>>>(P, qst, W4v, b4, W5v, b5, W6, b6, out);
}